// Round 20
// baseline (32.443 us; speedup 1.0000x reference)
//
#include <hip/hip_runtime.h>
#include <hip/hip_bf16.h>

// MADPSNet fused, round 20: r19 EXACT (32.13us best) + cross-layer B
// prefetch depth 2 -> 4, keeping the POST-epilogue issue point (r17/r19's
// proven placement). r18 bundled depth-4 WITH pre-epilogue issue and
// regressed; this isolates the depth variable. Coverage: F=1 layers (L2,L4)
// get k-steps 0..3 pre-loaded; F=2 layers (L1,L3) get k-steps 0..1.
// Cost: +8 VGPR across the barrier (watch WRITE_SIZE for spill).
// Carried: bias pre-k-loop hoist (r19, +0.13us), (MG,NG)=(1,16) L1-L3 /
// (2,8) L4, packed-B streams, swapped-operand MFMA + vector epilogue,
// XOR-swizzled activations, prep early-exit, agent=bid&7 XCD pinning.
// Closed axes: intra-loop scheduling 0/4, M-geometry 0/3, 32x32 MFMA 0/1,
// B-duplication 0/3, LDS DMA ring (race), pre-epilogue prefetch (r18).

typedef __attribute__((ext_vector_type(8))) short bf16x8;
typedef __attribute__((ext_vector_type(4))) float f32x4;

__device__ __forceinline__ ushort f2b(float x) {
    __hip_bfloat16 h = __float2bfloat16(x);
    return *reinterpret_cast<ushort*>(&h);
}

// ------------------------------------------------------------------ prep ---
// W[e][K][N] fp32 -> Wp[e][fg][s][lane][j] bf16 (MFMA fragment order):
//   n = fg*16 + (lane&15), k = s*32 + (lane>>4)*8 + j,  s = 0..K/32-1
// Early-exit: skip experts not selected by any agent.
__global__ __launch_bounds__(256)
void prep_weights(const float* __restrict__ Ws1, const float* __restrict__ Ws2,
                  const float* __restrict__ Wd1, const float* __restrict__ Wd2,
                  const int* __restrict__ sel_s, const int* __restrict__ sel_d,
                  ushort* __restrict__ W1p, ushort* __restrict__ W2p,
                  ushort* __restrict__ W3p, ushort* __restrict__ W4p)
{
    const int layer = blockIdx.z;
    const int e  = blockIdx.y;
    const int fg = blockIdx.x;

    const int* sel = (layer <= 1) ? sel_s : sel_d;
    bool used = false;
    #pragma unroll
    for (int a = 0; a < 8; ++a) used |= (sel[a] == e);
    if (!used) return;

    const float* W; ushort* Wp; int K, N;
    if (layer == 0)      { W = Ws1; Wp = W1p; K = 256; N = 512; }
    else if (layer == 1) { W = Ws2; Wp = W2p; K = 512; N = 256; }
    else if (layer == 2) { W = Wd1; Wp = W3p; K = 256; N = 512; }
    else                 { W = Wd2; Wp = W4p; K = 512; N = 128; }
    if (fg >= N / 16) return;
    const int NK = K / 32;
    W += (size_t)e * K * N;

    __shared__ float tile[512][17];
    const int tid = threadIdx.x;
    const int n0 = fg * 16;
    for (int idx = tid; idx < K * 16; idx += 256)
        tile[idx >> 4][idx & 15] = W[(size_t)(idx >> 4) * N + n0 + (idx & 15)];
    __syncthreads();
    ushort* dst = Wp + (((size_t)e * (N / 16) + fg) * NK) * 512;
    for (int w = tid; w < NK * 64; w += 256) {
        const int s    = w >> 6;
        const int lane = w & 63;
        const int c    = lane & 15;
        const int kb   = s * 32 + ((lane >> 4) << 3);
        bf16x8 v;
        #pragma unroll
        for (int j = 0; j < 8; ++j)
            v[j] = (short)f2b(tile[kb + j][c]);
        *reinterpret_cast<bf16x8*>(&dst[(size_t)w * 8]) = v;
    }
}

// --------------------------------------------------------------- B peek ---
// Load fragment j (stream order: j = s*F + f) of this wave's B stream.
template<int K, int N, int MG>
__device__ __forceinline__ bf16x8 peekB(const ushort* __restrict__ Wp,
                                        int wid, int lane, int j)
{
    constexpr int NG = 16 / MG;
    constexpr int F  = N / 16 / NG;
    constexpr int NK = K / 32;
    const int wc = wid % NG;
    const ushort* bBase = Wp + ((size_t)(wc * F) * NK) * 512 + (size_t)lane * 8;
    const int f = j % F, s = j / F;
    return *reinterpret_cast<const bf16x8*>(bBase + ((size_t)f * NK + s) * 512);
}

// ----------------------------------------------------------- fused layer ---
// A: LDS [64][K] bf16 swizzled. B: packed global (fragment order).
// 16 waves: MG row-groups x NG col-groups (MG*NG=16), F=N/16/NG frags/wave.
// pb0..pb3 = fragments j=0..3 (prefetched post-epilogue by the caller,
// before the barrier). Bias float4s hoisted before the k-loop (r19).
template<int K, int N, int MG, int RELU>
__device__ __forceinline__ void layer_mlp(
    const ushort* __restrict__ Wp, const float* __restrict__ bias,
    const ushort* __restrict__ sIn, ushort* __restrict__ sOut,
    float* __restrict__ gOut, int wid, int lane,
    bf16x8 pb0, bf16x8 pb1, bf16x8 pb2, bf16x8 pb3)
{
    constexpr int NG = 16 / MG;          // col groups
    constexpr int F  = N / 16 / NG;      // frags per wave
    constexpr int M4 = 4 / MG;           // m-frags per wave
    constexpr int NK = K / 32;           // k-steps
    const int r15 = lane & 15, lh = lane >> 4;
    const int wc = wid % NG, wr = wid / NG;
    const int rowBase = wr * (64 / MG);

    const ushort* bBase = Wp + ((size_t)(wc * F) * NK) * 512 + (size_t)lane * 8;

    // bias hoist (r19): no fresh L2 access after the last MFMA
    float4 bv[F];
    #pragma unroll
    for (int f = 0; f < F; ++f)
        bv[f] = *reinterpret_cast<const float4*>(
            &bias[(wc * F + f) * 16 + lh * 4]);

    f32x4 acc[M4][F];
    #pragma unroll
    for (int m = 0; m < M4; ++m)
        #pragma unroll
        for (int f = 0; f < F; ++f)
            acc[m][f] = (f32x4){0.f, 0.f, 0.f, 0.f};

    #pragma unroll
    for (int s = 0; s < NK; ++s) {
        const int k0 = s * 32;
        bf16x8 a[M4];
        #pragma unroll
        for (int m = 0; m < M4; ++m) {
            const int row  = rowBase + m * 16 + r15;
            const int phys = ((k0 >> 3) + lh) ^ (row & 7);
            a[m] = *reinterpret_cast<const bf16x8*>(
                reinterpret_cast<const char*>(sIn) + row * (K * 2) + (phys << 4));
        }
        bf16x8 b[F];
        #pragma unroll
        for (int f = 0; f < F; ++f) {
            const int j = s * F + f;                 // compile-time (unrolled)
            if (j == 0)      b[f] = pb0;             // prefetched pre-barrier
            else if (j == 1) b[f] = pb1;
            else if (j == 2) b[f] = pb2;
            else if (j == 3) b[f] = pb3;
            else b[f] = *reinterpret_cast<const bf16x8*>(
                     bBase + ((size_t)f * NK + s) * 512);
        }
        // swapped operands: lane holds (row = lane&15, 4 consecutive cols)
        #pragma unroll
        for (int m = 0; m < M4; ++m)
            #pragma unroll
            for (int f = 0; f < F; ++f)
                acc[m][f] = __builtin_amdgcn_mfma_f32_16x16x32_bf16(
                    b[f], a[m], acc[m][f], 0, 0, 0);
    }

    // epilogue: lane holds (row = rowBase+m*16+r15, cols cbase..cbase+3)
    #pragma unroll
    for (int f = 0; f < F; ++f) {
        const int cbase = (wc * F + f) * 16 + lh * 4;
        #pragma unroll
        for (int m = 0; m < M4; ++m) {
            const int row = rowBase + m * 16 + r15;
            float v0 = acc[m][f][0] + bv[f].x;
            float v1 = acc[m][f][1] + bv[f].y;
            float v2 = acc[m][f][2] + bv[f].z;
            float v3 = acc[m][f][3] + bv[f].w;
            if (RELU) {
                v0 = fmaxf(v0, 0.f); v1 = fmaxf(v1, 0.f);
                v2 = fmaxf(v2, 0.f); v3 = fmaxf(v3, 0.f);
            }
            if (gOut) {
                *reinterpret_cast<float4*>(&gOut[(size_t)row * N + cbase]) =
                    (float4){v0, v1, v2, v3};
            } else {
                const uint lo = ((uint)f2b(v1) << 16) | (uint)f2b(v0);
                const uint hi = ((uint)f2b(v3) << 16) | (uint)f2b(v2);
                const int byteoff = row * (N * 2) +
                    ((((cbase >> 3) ^ (row & 7))) << 4) + ((cbase & 7) << 1);
                *reinterpret_cast<uint2*>(
                    reinterpret_cast<char*>(sOut) + byteoff) = (uint2){lo, hi};
            }
        }
    }
}

// ----------------------------------------------------------- fused kernel ---
__global__ __launch_bounds__(1024, 4)
void madps_fused(const float* __restrict__ X,
                 const int* __restrict__ sel_s, const int* __restrict__ sel_d,
                 const ushort* __restrict__ W1p, const ushort* __restrict__ W2p,
                 const ushort* __restrict__ W3p, const ushort* __restrict__ W4p,
                 const float* __restrict__ bs1, const float* __restrict__ bs2,
                 const float* __restrict__ bd1, const float* __restrict__ bd2,
                 float* __restrict__ out)
{
    constexpr int S = 256, H1 = 512, H2 = 256, D1 = 512, D2 = 128;

    __shared__ __align__(16) ushort buf0[64 * 256];   // 32 KB: X, then sh
    __shared__ __align__(16) ushort buf1[64 * 512];   // 64 KB: h, then d

    const int bid   = blockIdx.x;
    const int agent = bid & 7;          // agent == XCD -> weights L2-resident
    const int rb    = bid >> 3;         // row-block within agent (0..31)
    const int tid   = threadIdx.x;
    const int lane  = tid & 63;
    const int wid   = tid >> 6;         // 0..15

    const long long es = sel_s[agent];
    const long long ed = sel_d[agent];

    const ushort* W1e = W1p + (size_t)es * ((H1 / 16) * (S  / 32) * 512);
    const ushort* W2e = W2p + (size_t)es * ((H2 / 16) * (H1 / 32) * 512);
    const ushort* W3e = W3p + (size_t)ed * ((D1 / 16) * (H2 / 32) * 512);
    const ushort* W4e = W4p + (size_t)ed * ((D2 / 16) * (D1 / 32) * 512);

    const float* Xa = X + ((size_t)agent * 2048 + (size_t)rb * 64) * S;

    // prefetch L1's first four B frags (overlaps X-staging + barrier)
    bf16x8 pb0 = peekB<S, H1, 1>(W1e, wid, lane, 0);
    bf16x8 pb1 = peekB<S, H1, 1>(W1e, wid, lane, 1);
    bf16x8 pb2 = peekB<S, H1, 1>(W1e, wid, lane, 2);
    bf16x8 pb3 = peekB<S, H1, 1>(W1e, wid, lane, 3);

    // ---- stage X [64][256] fp32 -> buf0 bf16 (swizzled) ----
    #pragma unroll
    for (int i = 0; i < 4; ++i) {
        const int flat4 = i * 1024 + tid;       // float4 index, 64/row
        const int row = flat4 >> 6;
        const int c4  = flat4 & 63;
        const float4 v = reinterpret_cast<const float4*>(Xa)[flat4];
        ushort4 o;
        o.x = f2b(v.x); o.y = f2b(v.y); o.z = f2b(v.z); o.w = f2b(v.w);
        const int byteoff = (((c4 >> 1) ^ (row & 7)) << 4) | ((c4 & 1) << 3);
        *reinterpret_cast<ushort4*>(
            reinterpret_cast<char*>(buf0) + row * 512 + byteoff) = o;
    }
    __syncthreads();

    // L1: X(buf0, K=256) @ W1e -> relu -> h(buf1, N=512)
    layer_mlp<S, H1, 1, 1>(W1e, bs1 + es * H1, buf0, buf1, nullptr,
                           wid, lane, pb0, pb1, pb2, pb3);
    pb0 = peekB<H1, H2, 1>(W2e, wid, lane, 0);       // prefetch L2 B (post-epi)
    pb1 = peekB<H1, H2, 1>(W2e, wid, lane, 1);
    pb2 = peekB<H1, H2, 1>(W2e, wid, lane, 2);
    pb3 = peekB<H1, H2, 1>(W2e, wid, lane, 3);
    __syncthreads();
    // L2: h(buf1, K=512) @ W2e -> relu -> sh(buf0, N=256)
    layer_mlp<H1, H2, 1, 1>(W2e, bs2 + es * H2, buf1, buf0, nullptr,
                            wid, lane, pb0, pb1, pb2, pb3);
    pb0 = peekB<H2, D1, 1>(W3e, wid, lane, 0);       // prefetch L3 B
    pb1 = peekB<H2, D1, 1>(W3e, wid, lane, 1);
    pb2 = peekB<H2, D1, 1>(W3e, wid, lane, 2);
    pb3 = peekB<H2, D1, 1>(W3e, wid, lane, 3);
    __syncthreads();
    // L3: sh(buf0, K=256) @ W3e -> relu -> d(buf1, N=512)
    layer_mlp<H2, D1, 1, 1>(W3e, bd1 + ed * D1, buf0, buf1, nullptr,
                            wid, lane, pb0, pb1, pb2, pb3);
    pb0 = peekB<D1, D2, 2>(W4e, wid, lane, 0);       // prefetch L4 B
    pb1 = peekB<D1, D2, 2>(W4e, wid, lane, 1);
    pb2 = peekB<D1, D2, 2>(W4e, wid, lane, 2);
    pb3 = peekB<D1, D2, 2>(W4e, wid, lane, 3);
    __syncthreads();
    // L4: d(buf1, K=512) @ W4e + bias -> out fp32 [64][128]  (2x8 M-split)
    float* outP = out + ((size_t)agent * 2048 + (size_t)rb * 64) * D2;
    layer_mlp<D1, D2, 2, 0>(W4e, bd2 + ed * D2, buf1, nullptr, outP,
                            wid, lane, pb0, pb1, pb2, pb3);
}

// --------------------------------------------------------------- launch ---
extern "C" void kernel_launch(void* const* d_in, const int* in_sizes, int n_in,
                              void* d_out, int out_size, void* d_ws, size_t ws_size,
                              hipStream_t stream)
{
    constexpr int E = 8, S = 256, H1 = 512, H2 = 256, D1 = 512, D2 = 128;

    const float* inputs = (const float*)d_in[0];
    const int*   sel_s  = (const int*)d_in[1];
    const int*   sel_d  = (const int*)d_in[2];
    const float* Ws1 = (const float*)d_in[3];
    const float* bs1 = (const float*)d_in[4];
    const float* Ws2 = (const float*)d_in[5];
    const float* bs2 = (const float*)d_in[6];
    const float* Wd1 = (const float*)d_in[7];
    const float* bd1 = (const float*)d_in[8];
    const float* Wd2 = (const float*)d_in[9];
    const float* bd2 = (const float*)d_in[10];
    float* out = (float*)d_out;

    // workspace: packed bf16 weights
    ushort* W1p = (ushort*)d_ws;
    ushort* W2p = W1p + (size_t)E * S * H1;
    ushort* W3p = W2p + (size_t)E * H1 * H2;
    ushort* W4p = W3p + (size_t)E * H2 * D1;

    prep_weights<<<dim3(32, E, 4), 256, 0, stream>>>(
        Ws1, Ws2, Wd1, Wd2, sel_s, sel_d, W1p, W2p, W3p, W4p);

    madps_fused<<<dim3(256), dim3(1024), 0, stream>>>(
        inputs, sel_s, sel_d, W1p, W2p, W3p, W4p,
        bs1, bs2, bd1, bd2, out);
}

// Round 21
// 31.899 us; speedup vs baseline: 1.0170x; 1.0170x over previous
//
#include <hip/hip_runtime.h>
#include <hip/hip_bf16.h>

// MADPSNet fused — FINAL (r19 structure, verified best: 32.13us).
// 224.7 -> 32.13us over 20 rounds. Structure:
//  - expert-gather: compute ONLY the selected expert per agent (8x less work
//    than the reference's all-experts-then-gather)
//  - prep: transpose+cast weights to bf16 MFMA-fragment order [fg][s][lane][8]
//    (contiguous coalesced 1KB wave-streams), early-exit unselected experts
//  - fused kernel: all 4 layers in one launch; activations live in LDS
//    (96KB, XOR-swizzled both sides); M=64 rows/block, 256 blocks,
//    1024 thr = 16 waves = 4 waves/SIMD (TLP is the latency-hiding that
//    works; r8 +30%); col-split (MG,NG)=(1,16) minimizes B-L2 traffic
//    (hypersensitive: all B-duplication variants regressed, r5/r11/r16)
//  - swapped-operand MFMA mfma(b,a,acc): transposed C/D puts 4 consecutive
//    cols per lane -> vector epilogue (uint2 LDS writes / float4 stores)
//  - cross-layer B prefetch depth 2, post-epilogue issue (r17 +1.4us;
//    depth 4 and pre-epilogue variants both regressed)
//  - bias float4s hoisted before k-loop (r19 +0.13us)
//  - agent = bid&7 -> each XCD's L2 holds one agent's ~918KB weights
// Falsified axes (do not revisit): intra-loop scheduling fences/rings/
// setprio (0/5), M=32 geometry (0/3), 32x32 MFMA (0/1), B-duplication (0/3),
// wave-private global_load_lds ring (race + traffic-negative).

typedef __attribute__((ext_vector_type(8))) short bf16x8;
typedef __attribute__((ext_vector_type(4))) float f32x4;

__device__ __forceinline__ ushort f2b(float x) {
    __hip_bfloat16 h = __float2bfloat16(x);
    return *reinterpret_cast<ushort*>(&h);
}

// ------------------------------------------------------------------ prep ---
// W[e][K][N] fp32 -> Wp[e][fg][s][lane][j] bf16 (MFMA fragment order):
//   n = fg*16 + (lane&15), k = s*32 + (lane>>4)*8 + j,  s = 0..K/32-1
// Early-exit: skip experts not selected by any agent.
__global__ __launch_bounds__(256)
void prep_weights(const float* __restrict__ Ws1, const float* __restrict__ Ws2,
                  const float* __restrict__ Wd1, const float* __restrict__ Wd2,
                  const int* __restrict__ sel_s, const int* __restrict__ sel_d,
                  ushort* __restrict__ W1p, ushort* __restrict__ W2p,
                  ushort* __restrict__ W3p, ushort* __restrict__ W4p)
{
    const int layer = blockIdx.z;
    const int e  = blockIdx.y;
    const int fg = blockIdx.x;

    const int* sel = (layer <= 1) ? sel_s : sel_d;
    bool used = false;
    #pragma unroll
    for (int a = 0; a < 8; ++a) used |= (sel[a] == e);
    if (!used) return;

    const float* W; ushort* Wp; int K, N;
    if (layer == 0)      { W = Ws1; Wp = W1p; K = 256; N = 512; }
    else if (layer == 1) { W = Ws2; Wp = W2p; K = 512; N = 256; }
    else if (layer == 2) { W = Wd1; Wp = W3p; K = 256; N = 512; }
    else                 { W = Wd2; Wp = W4p; K = 512; N = 128; }
    if (fg >= N / 16) return;
    const int NK = K / 32;
    W += (size_t)e * K * N;

    __shared__ float tile[512][17];
    const int tid = threadIdx.x;
    const int n0 = fg * 16;
    for (int idx = tid; idx < K * 16; idx += 256)
        tile[idx >> 4][idx & 15] = W[(size_t)(idx >> 4) * N + n0 + (idx & 15)];
    __syncthreads();
    ushort* dst = Wp + (((size_t)e * (N / 16) + fg) * NK) * 512;
    for (int w = tid; w < NK * 64; w += 256) {
        const int s    = w >> 6;
        const int lane = w & 63;
        const int c    = lane & 15;
        const int kb   = s * 32 + ((lane >> 4) << 3);
        bf16x8 v;
        #pragma unroll
        for (int j = 0; j < 8; ++j)
            v[j] = (short)f2b(tile[kb + j][c]);
        *reinterpret_cast<bf16x8*>(&dst[(size_t)w * 8]) = v;
    }
}

// --------------------------------------------------------------- B peek ---
// Load fragment j (stream order: j = s*F + f) of this wave's B stream.
template<int K, int N, int MG>
__device__ __forceinline__ bf16x8 peekB(const ushort* __restrict__ Wp,
                                        int wid, int lane, int j)
{
    constexpr int NG = 16 / MG;
    constexpr int F  = N / 16 / NG;
    constexpr int NK = K / 32;
    const int wc = wid % NG;
    const ushort* bBase = Wp + ((size_t)(wc * F) * NK) * 512 + (size_t)lane * 8;
    const int f = j % F, s = j / F;
    return *reinterpret_cast<const bf16x8*>(bBase + ((size_t)f * NK + s) * 512);
}

// ----------------------------------------------------------- fused layer ---
// A: LDS [64][K] bf16 swizzled. B: packed global (fragment order).
// 16 waves: MG row-groups x NG col-groups (MG*NG=16), F=N/16/NG frags/wave.
// pb0/pb1 = fragments j=0,1 (prefetched pre-barrier by the caller).
template<int K, int N, int MG, int RELU>
__device__ __forceinline__ void layer_mlp(
    const ushort* __restrict__ Wp, const float* __restrict__ bias,
    const ushort* __restrict__ sIn, ushort* __restrict__ sOut,
    float* __restrict__ gOut, int wid, int lane,
    bf16x8 pb0, bf16x8 pb1)
{
    constexpr int NG = 16 / MG;          // col groups
    constexpr int F  = N / 16 / NG;      // frags per wave
    constexpr int M4 = 4 / MG;           // m-frags per wave
    constexpr int NK = K / 32;           // k-steps
    const int r15 = lane & 15, lh = lane >> 4;
    const int wc = wid % NG, wr = wid / NG;
    const int rowBase = wr * (64 / MG);

    const ushort* bBase = Wp + ((size_t)(wc * F) * NK) * 512 + (size_t)lane * 8;

    // bias hoist: no fresh L2 access after the last MFMA
    float4 bv[F];
    #pragma unroll
    for (int f = 0; f < F; ++f)
        bv[f] = *reinterpret_cast<const float4*>(
            &bias[(wc * F + f) * 16 + lh * 4]);

    f32x4 acc[M4][F];
    #pragma unroll
    for (int m = 0; m < M4; ++m)
        #pragma unroll
        for (int f = 0; f < F; ++f)
            acc[m][f] = (f32x4){0.f, 0.f, 0.f, 0.f};

    #pragma unroll
    for (int s = 0; s < NK; ++s) {
        const int k0 = s * 32;
        bf16x8 a[M4];
        #pragma unroll
        for (int m = 0; m < M4; ++m) {
            const int row  = rowBase + m * 16 + r15;
            const int phys = ((k0 >> 3) + lh) ^ (row & 7);
            a[m] = *reinterpret_cast<const bf16x8*>(
                reinterpret_cast<const char*>(sIn) + row * (K * 2) + (phys << 4));
        }
        bf16x8 b[F];
        #pragma unroll
        for (int f = 0; f < F; ++f) {
            const int j = s * F + f;                 // compile-time (unrolled)
            if (j == 0)      b[f] = pb0;             // prefetched pre-barrier
            else if (j == 1) b[f] = pb1;
            else b[f] = *reinterpret_cast<const bf16x8*>(
                     bBase + ((size_t)f * NK + s) * 512);
        }
        // swapped operands: lane holds (row = lane&15, 4 consecutive cols)
        #pragma unroll
        for (int m = 0; m < M4; ++m)
            #pragma unroll
            for (int f = 0; f < F; ++f)
                acc[m][f] = __builtin_amdgcn_mfma_f32_16x16x32_bf16(
                    b[f], a[m], acc[m][f], 0, 0, 0);
    }

    // epilogue: lane holds (row = rowBase+m*16+r15, cols cbase..cbase+3)
    #pragma unroll
    for (int f = 0; f < F; ++f) {
        const int cbase = (wc * F + f) * 16 + lh * 4;
        #pragma unroll
        for (int m = 0; m < M4; ++m) {
            const int row = rowBase + m * 16 + r15;
            float v0 = acc[m][f][0] + bv[f].x;
            float v1 = acc[m][f][1] + bv[f].y;
            float v2 = acc[m][f][2] + bv[f].z;
            float v3 = acc[m][f][3] + bv[f].w;
            if (RELU) {
                v0 = fmaxf(v0, 0.f); v1 = fmaxf(v1, 0.f);
                v2 = fmaxf(v2, 0.f); v3 = fmaxf(v3, 0.f);
            }
            if (gOut) {
                *reinterpret_cast<float4*>(&gOut[(size_t)row * N + cbase]) =
                    (float4){v0, v1, v2, v3};
            } else {
                const uint lo = ((uint)f2b(v1) << 16) | (uint)f2b(v0);
                const uint hi = ((uint)f2b(v3) << 16) | (uint)f2b(v2);
                const int byteoff = row * (N * 2) +
                    ((((cbase >> 3) ^ (row & 7))) << 4) + ((cbase & 7) << 1);
                *reinterpret_cast<uint2*>(
                    reinterpret_cast<char*>(sOut) + byteoff) = (uint2){lo, hi};
            }
        }
    }
}

// ----------------------------------------------------------- fused kernel ---
__global__ __launch_bounds__(1024, 4)
void madps_fused(const float* __restrict__ X,
                 const int* __restrict__ sel_s, const int* __restrict__ sel_d,
                 const ushort* __restrict__ W1p, const ushort* __restrict__ W2p,
                 const ushort* __restrict__ W3p, const ushort* __restrict__ W4p,
                 const float* __restrict__ bs1, const float* __restrict__ bs2,
                 const float* __restrict__ bd1, const float* __restrict__ bd2,
                 float* __restrict__ out)
{
    constexpr int S = 256, H1 = 512, H2 = 256, D1 = 512, D2 = 128;

    __shared__ __align__(16) ushort buf0[64 * 256];   // 32 KB: X, then sh
    __shared__ __align__(16) ushort buf1[64 * 512];   // 64 KB: h, then d

    const int bid   = blockIdx.x;
    const int agent = bid & 7;          // agent == XCD -> weights L2-resident
    const int rb    = bid >> 3;         // row-block within agent (0..31)
    const int tid   = threadIdx.x;
    const int lane  = tid & 63;
    const int wid   = tid >> 6;         // 0..15

    const long long es = sel_s[agent];
    const long long ed = sel_d[agent];

    const ushort* W1e = W1p + (size_t)es * ((H1 / 16) * (S  / 32) * 512);
    const ushort* W2e = W2p + (size_t)es * ((H2 / 16) * (H1 / 32) * 512);
    const ushort* W3e = W3p + (size_t)ed * ((D1 / 16) * (H2 / 32) * 512);
    const ushort* W4e = W4p + (size_t)ed * ((D2 / 16) * (D1 / 32) * 512);

    const float* Xa = X + ((size_t)agent * 2048 + (size_t)rb * 64) * S;

    // prefetch L1's first two B frags (overlaps X-staging + barrier)
    bf16x8 pb0 = peekB<S, H1, 1>(W1e, wid, lane, 0);
    bf16x8 pb1 = peekB<S, H1, 1>(W1e, wid, lane, 1);

    // ---- stage X [64][256] fp32 -> buf0 bf16 (swizzled) ----
    #pragma unroll
    for (int i = 0; i < 4; ++i) {
        const int flat4 = i * 1024 + tid;       // float4 index, 64/row
        const int row = flat4 >> 6;
        const int c4  = flat4 & 63;
        const float4 v = reinterpret_cast<const float4*>(Xa)[flat4];
        ushort4 o;
        o.x = f2b(v.x); o.y = f2b(v.y); o.z = f2b(v.z); o.w = f2b(v.w);
        const int byteoff = (((c4 >> 1) ^ (row & 7)) << 4) | ((c4 & 1) << 3);
        *reinterpret_cast<ushort4*>(
            reinterpret_cast<char*>(buf0) + row * 512 + byteoff) = o;
    }
    __syncthreads();

    // L1: X(buf0, K=256) @ W1e -> relu -> h(buf1, N=512)
    layer_mlp<S, H1, 1, 1>(W1e, bs1 + es * H1, buf0, buf1, nullptr,
                           wid, lane, pb0, pb1);
    pb0 = peekB<H1, H2, 1>(W2e, wid, lane, 0);       // prefetch L2 B
    pb1 = peekB<H1, H2, 1>(W2e, wid, lane, 1);
    __syncthreads();
    // L2: h(buf1, K=512) @ W2e -> relu -> sh(buf0, N=256)
    layer_mlp<H1, H2, 1, 1>(W2e, bs2 + es * H2, buf1, buf0, nullptr,
                            wid, lane, pb0, pb1);
    pb0 = peekB<H2, D1, 1>(W3e, wid, lane, 0);       // prefetch L3 B
    pb1 = peekB<H2, D1, 1>(W3e, wid, lane, 1);
    __syncthreads();
    // L3: sh(buf0, K=256) @ W3e -> relu -> d(buf1, N=512)
    layer_mlp<H2, D1, 1, 1>(W3e, bd1 + ed * D1, buf0, buf1, nullptr,
                            wid, lane, pb0, pb1);
    pb0 = peekB<D1, D2, 2>(W4e, wid, lane, 0);       // prefetch L4 B
    pb1 = peekB<D1, D2, 2>(W4e, wid, lane, 1);
    __syncthreads();
    // L4: d(buf1, K=512) @ W4e + bias -> out fp32 [64][128]  (2x8 M-split)
    float* outP = out + ((size_t)agent * 2048 + (size_t)rb * 64) * D2;
    layer_mlp<D1, D2, 2, 0>(W4e, bd2 + ed * D2, buf1, nullptr, outP,
                            wid, lane, pb0, pb1);
}

// --------------------------------------------------------------- launch ---
extern "C" void kernel_launch(void* const* d_in, const int* in_sizes, int n_in,
                              void* d_out, int out_size, void* d_ws, size_t ws_size,
                              hipStream_t stream)
{
    constexpr int E = 8, S = 256, H1 = 512, H2 = 256, D1 = 512, D2 = 128;

    const float* inputs = (const float*)d_in[0];
    const int*   sel_s  = (const int*)d_in[1];
    const int*   sel_d  = (const int*)d_in[2];
    const float* Ws1 = (const float*)d_in[3];
    const float* bs1 = (const float*)d_in[4];
    const float* Ws2 = (const float*)d_in[5];
    const float* bs2 = (const float*)d_in[6];
    const float* Wd1 = (const float*)d_in[7];
    const float* bd1 = (const float*)d_in[8];
    const float* Wd2 = (const float*)d_in[9];
    const float* bd2 = (const float*)d_in[10];
    float* out = (float*)d_out;

    // workspace: packed bf16 weights
    ushort* W1p = (ushort*)d_ws;
    ushort* W2p = W1p + (size_t)E * S * H1;
    ushort* W3p = W2p + (size_t)E * H1 * H2;
    ushort* W4p = W3p + (size_t)E * H2 * D1;

    prep_weights<<<dim3(32, E, 4), 256, 0, stream>>>(
        Ws1, Ws2, Wd1, Wd2, sel_s, sel_d, W1p, W2p, W3p, W4p);

    madps_fused<<<dim3(256), dim3(1024), 0, stream>>>(
        inputs, sel_s, sel_d, W1p, W2p, W3p, W4p,
        bs1, bs2, bd1, bd2, out);
}